// Round 9
// baseline (2464.478 us; speedup 1.0000x reference)
//
#include <hip/hip_runtime.h>
#include <hip/hip_bf16.h>

#define NN 100000
#define NE 1600000
#define NCHUNK 391   // ceil(100000/256)

typedef unsigned short u16;
typedef unsigned int   u32;

__device__ __forceinline__ float bfu(u32 v){ union{u32 i; float f;} w; w.i = v<<16; return w.f; }
__device__ __forceinline__ float bf_lo(u32 u){ return bfu(u & 0xffffu); }
__device__ __forceinline__ float bf_hi(u32 u){ return bfu(u >> 16); }
__device__ __forceinline__ float bf16f(u16 u){ return bfu((u32)u); }
__device__ __forceinline__ u16 f2bf(float f){
    union{float f; u32 i;} w; w.f = f;
    u32 r = (w.i + 0x7fffu + ((w.i >> 16) & 1u)) >> 16;   // RNE
    return (u16)r;
}
__device__ __forceinline__ u32 pack2(float lo, float hi){
    return (u32)f2bf(lo) | ((u32)f2bf(hi) << 16);
}
// uniform-lane broadcast via v_readlane (SGPR result) — replaces ds_bpermute shfl
__device__ __forceinline__ float bcastf(float x, int l){
    return __int_as_float(__builtin_amdgcn_readlane(__float_as_int(x), l));
}
__device__ __forceinline__ int bcasti(int x, int l){
    return __builtin_amdgcn_readlane(x, l);
}

template<int IS32>
__device__ __forceinline__ float ldx(const void* p, int i){
    if (IS32) return ((const float*)p)[i];
    else      return bf16f(((const u16*)p)[i]);
}

// ---------------- dtype sniff: fp32 (1) vs bf16 (0) ----------------
__global__ void k_sniff(const u32* __restrict__ x, int* __restrict__ flag){
    __shared__ int cnt[256];
    int t = threadIdx.x;
    int bad = 0;
    for (int i = t; i < 512; i += 256){
        u32 w = x[i];
        u32 lo = w & 0xffffu;
        u32 e = (lo >> 7) & 0xffu;
        bool sane = (lo == 0u) || (lo == 0x8000u) || (e >= 85u && e <= 133u);
        if (!sane) bad++;
    }
    cnt[t] = bad; __syncthreads();
    for (int s = 128; s > 0; s >>= 1){
        if (t < s) cnt[t] += cnt[t+s];
        __syncthreads();
    }
    if (t == 0) flag[0] = (cnt[0] > 100) ? 1 : 0;
}

// ---------------- CSR build (dtype-independent) ----------------

__global__ void k_deg(const int* __restrict__ dst, int* __restrict__ deg){
    int stride = gridDim.x * blockDim.x;
    for (int i = blockIdx.x*blockDim.x + threadIdx.x; i < NE; i += stride){
        int d = dst[i];
        if ((unsigned)d < (unsigned)NN) atomicAdd(&deg[d], 1);
    }
}

__global__ void k_csum(const int* __restrict__ deg, int* __restrict__ csum){
    __shared__ int sdata[256];
    int t = threadIdx.x;
    int idx = blockIdx.x*256 + t;
    sdata[t] = (idx < NN) ? deg[idx] : 0;
    __syncthreads();
    for (int s = 128; s > 0; s >>= 1){
        if (t < s) sdata[t] += sdata[t+s];
        __syncthreads();
    }
    if (t == 0) csum[blockIdx.x] = sdata[0];
}

__global__ void k_scan_chunks(const int* __restrict__ csum, int* __restrict__ coff){
    __shared__ int s[512];
    int t = threadIdx.x;
    int v = (t < NCHUNK) ? csum[t] : 0;
    s[t] = v; __syncthreads();
    int x = v;
    for (int off = 1; off < 512; off <<= 1){
        int y = (t >= off) ? s[t-off] : 0;
        __syncthreads();
        x += y; s[t] = x;
        __syncthreads();
    }
    if (t < NCHUNK) coff[t] = x - v;   // exclusive
}

__global__ void k_rowptr(const int* __restrict__ deg, const int* __restrict__ coff,
                         int* __restrict__ row_ptr){
    __shared__ int s[256];
    int t = threadIdx.x, b = blockIdx.x;
    int idx = b*256 + t;
    int v = (idx < NN) ? deg[idx] : 0;
    s[t] = v; __syncthreads();
    int x = v;
    for (int off = 1; off < 256; off <<= 1){
        int y = (t >= off) ? s[t-off] : 0;
        __syncthreads();
        x += y; s[t] = x;
        __syncthreads();
    }
    if (idx < NN)       row_ptr[idx] = coff[b] + x - v;   // exclusive
    if (idx == NN - 1)  row_ptr[NN]  = coff[b] + x;       // total = NE
}

__global__ void k_scatter(const int* __restrict__ src, const int* __restrict__ dst,
                          const int* __restrict__ row_ptr, int* __restrict__ fill,
                          int2* __restrict__ pair_sorted){
    int stride = gridDim.x * blockDim.x;
    for (int i = blockIdx.x*blockDim.x + threadIdx.x; i < NE; i += stride){
        int d = dst[i];
        if ((unsigned)d >= (unsigned)NN) continue;
        int p = row_ptr[d] + atomicAdd(&fill[d], 1);
        if ((unsigned)p < (unsigned)NE){
            int s = src[i];
            if ((unsigned)s >= (unsigned)NN) s = 0;
            pair_sorted[p] = make_int2(s, i);
        }
    }
}

// ---------------- edge-attr reorder into p-sorted order (bf16 packed) ----------------
template<int IS32>
__global__ __launch_bounds__(256) void k_reorder(const int2* __restrict__ pair_sorted,
                                                 const void* __restrict__ ea,
                                                 const int* __restrict__ flg,
                                                 uint4* __restrict__ ea_srt){
    if (flg[0] != IS32) return;
    int stride = gridDim.x * blockDim.x;
    for (int p = blockIdx.x*blockDim.x + threadIdx.x; p < NE; p += stride){
        int eid = pair_sorted[p].y;
        if ((unsigned)eid >= (unsigned)NE) eid = 0;
        uint4 o0, o1;
        if (IS32){
            const float4* er = (const float4*)ea + (size_t)eid*4;
            float4 u0 = er[0], u1 = er[1], u2 = er[2], u3 = er[3];
            o0.x = pack2(u0.x, u0.y); o0.y = pack2(u0.z, u0.w);
            o0.z = pack2(u1.x, u1.y); o0.w = pack2(u1.z, u1.w);
            o1.x = pack2(u2.x, u2.y); o1.y = pack2(u2.z, u2.w);
            o1.z = pack2(u3.x, u3.y); o1.w = pack2(u3.z, u3.w);
        } else {
            const uint4* er = (const uint4*)ea + (size_t)eid*2;
            o0 = er[0]; o1 = er[1];
        }
        ea_srt[(size_t)p*2 + 0] = o0;
        ea_srt[(size_t)p*2 + 1] = o1;
    }
}

// ---------------- input projection ----------------
template<int IS32>
__global__ __launch_bounds__(256) void k_proj(const void* __restrict__ x,
                                              const void* __restrict__ w,
                                              const void* __restrict__ b,
                                              const int* __restrict__ flg,
                                              u16* __restrict__ h){
    if (flg[0] != IS32) return;
    int lane = threadIdx.x & 63;
    int wid  = (blockIdx.x*256 + threadIdx.x) >> 6;
    int nw   = (gridDim.x*256) >> 6;
    float wr[32];
    #pragma unroll
    for (int k = 0; k < 32; k++) wr[k] = ldx<IS32>(w, k*64 + lane);
    float bias = ldx<IS32>(b, lane);
    for (int node = wid; node < NN; node += nw){
        float acc = bias;
        if (IS32){
            const float* xr = (const float*)x + (size_t)node*32;
            #pragma unroll
            for (int k = 0; k < 32; k++) acc = fmaf(xr[k], wr[k], acc);
        } else {
            const u16* xr = (const u16*)x + (size_t)node*32;
            #pragma unroll
            for (int k = 0; k < 32; k++) acc = fmaf(bf16f(xr[k]), wr[k], acc);
        }
        float accn = __shfl_xor(acc, 1, 64);
        if (!(lane & 1))
            ((u32*)h)[(size_t)node*32 + (lane >> 1)] = pack2(acc, accn);
    }
}

// 16-channel dot of one bf16-packed edge-attr row with per-lane ew column
__device__ __forceinline__ float edot(uint4 a, uint4 b, const float* ewr, float ebr){
    float e = ebr;
    e = fmaf(bf_lo(a.x), ewr[0],  e); e = fmaf(bf_hi(a.x), ewr[1],  e);
    e = fmaf(bf_lo(a.y), ewr[2],  e); e = fmaf(bf_hi(a.y), ewr[3],  e);
    e = fmaf(bf_lo(a.z), ewr[4],  e); e = fmaf(bf_hi(a.z), ewr[5],  e);
    e = fmaf(bf_lo(a.w), ewr[6],  e); e = fmaf(bf_hi(a.w), ewr[7],  e);
    e = fmaf(bf_lo(b.x), ewr[8],  e); e = fmaf(bf_hi(b.x), ewr[9],  e);
    e = fmaf(bf_lo(b.y), ewr[10], e); e = fmaf(bf_hi(b.y), ewr[11], e);
    e = fmaf(bf_lo(b.z), ewr[12], e); e = fmaf(bf_hi(b.z), ewr[13], e);
    e = fmaf(bf_lo(b.w), ewr[14], e); e = fmaf(bf_hi(b.w), ewr[15], e);
    return e;
}

// ================= FULLY-FUSED LAYER (single pass, no msg buffer) =================
// Round-9 changes vs round 8:
//  - 16-edge tiles (avg degree ~16 -> typically ONE tile per node)
//  - all 16 random h-row gathers preloaded into registers back-to-back
//    (clamped tail indices, no branches) -> guaranteed 16 lines in flight/wave
//  - __launch_bounds__(256,4) + grid 1024 -> 16 waves/CU
template<int IS32>
__global__ __launch_bounds__(256, 4) void k_fused(
    const u16*   __restrict__ h_in,
    const int*   __restrict__ row_ptr,
    const int2*  __restrict__ pair_sorted,
    const uint4* __restrict__ ea_srt,
    const void* __restrict__ ew, const void* __restrict__ eb,
    const void* __restrict__ w1, const void* __restrict__ b1,
    const void* __restrict__ g,  const void* __restrict__ bb,
    const void* __restrict__ w2, const void* __restrict__ b2,
    const int* __restrict__ flg,
    u16* __restrict__ h_out)
{
    if (flg[0] != IS32) return;

    __shared__ u32 w1p[64*64];       // 16 KB: lo=w1[k][c], hi=w1[k][c+64]
    __shared__ u32 w2p[64*64];       // 16 KB: lo=w2[k][c], hi=w2[k+64][c]
    __shared__ u16 sbuf[4][4*64];    // per-wave 512B output transpose scratch

    int t = threadIdx.x;
    for (int i = t; i < 64*64; i += 256){
        int k = i >> 6, c = i & 63;
        u32 lo1, hi1, lo2, hi2;
        if (IS32){
            lo1 = f2bf(((const float*)w1)[k*128 + c]);
            hi1 = f2bf(((const float*)w1)[k*128 + c + 64]);
            lo2 = f2bf(((const float*)w2)[k*64 + c]);
            hi2 = f2bf(((const float*)w2)[(k+64)*64 + c]);
        } else {
            lo1 = ((const u16*)w1)[k*128 + c];
            hi1 = ((const u16*)w1)[k*128 + c + 64];
            lo2 = ((const u16*)w2)[k*64 + c];
            hi2 = ((const u16*)w2)[(k+64)*64 + c];
        }
        w1p[i] = lo1 | (hi1 << 16);
        w2p[i] = lo2 | (hi2 << 16);
    }
    __syncthreads();

    int lane  = t & 63;
    int wslot = t >> 6;
    u16* sb   = sbuf[wslot];

    float ewr[16];
    #pragma unroll
    for (int k = 0; k < 16; k++) ewr[k] = ldx<IS32>(ew, k*64 + lane);
    float ebr = ldx<IS32>(eb, lane);
    const float BNS = 0.9999950000374997f;   // 1/sqrt(1+1e-5)
    float b1a = ldx<IS32>(b1, lane), b1b = ldx<IS32>(b1, lane+64);
    float ga  = ldx<IS32>(g, lane)*BNS,  gb  = ldx<IS32>(g, lane+64)*BNS;
    float bba = ldx<IS32>(bb, lane),     bbb = ldx<IS32>(bb, lane+64);
    float b2r = ldx<IS32>(b2, lane);

    // contiguous node sub-range for this wave
    int npb = (NN + gridDim.x - 1) / gridDim.x;
    int bn0 = blockIdx.x * npb;
    int bn1 = bn0 + npb; if (bn1 > NN) bn1 = NN;
    int wnpb = (npb + 3) >> 2;
    int wn0 = bn0 + wslot * wnpb;
    int wn1 = wn0 + wnpb; if (wn1 > bn1) wn1 = bn1;

    bool odd = (lane & 1);
    int hw_i = lane >> 1;

    for (int nb = wn0; nb < wn1; nb += 4){
        int cntn = wn1 - nb; if (cntn > 4) cntn = 4;
        float outv[4];

        for (int j = 0; j < 4; ++j){
            if (j >= cntn){ outv[j] = 0.f; continue; }
            int node = nb + j;
            int q0 = row_ptr[node], q1 = row_ptr[node+1];
            if (q0 < 0) q0 = 0;
            if (q1 > NE) q1 = NE;
            u32 hwv = ((const u32*)h_in)[(size_t)node*32 + hw_i];
            float hself = odd ? bf_hi(hwv) : bf_lo(hwv);

            float sw = 0.f, swm = 0.f;
            for (int qb = q0; qb < q1; qb += 16){
                int nv = q1 - qb; if (nv > 16) nv = 16;
                // 16 src ids via one cooperative 128B load (lanes 0..15)
                int sp = 0;
                if (lane < 16){
                    int q = qb + lane; if (q >= q1) q = q1 - 1;
                    sp = pair_sorted[q].x;
                    if ((unsigned)sp >= (unsigned)NN) sp = 0;
                }
                // preload ALL 16 h-rows back-to-back (clamped tail -> no branches)
                // guarantees 16 independent 128B lines in flight per wave
                u32 hr[16];
                #pragma unroll
                for (int e = 0; e < 16; ++e){
                    int s = bcasti(sp, e);             // SGPR base -> SALU addressing
                    hr[e] = ((const u32*)h_in)[(size_t)s*32 + hw_i];
                }
                // compute: sequential 32B broadcast ea reads + edot + exp + reduce
                #pragma unroll
                for (int e = 0; e < 16; ++e){
                    if (e < nv){                       // wave-uniform predicate
                        uint4 A = ea_srt[(size_t)(qb+e)*2];
                        uint4 B = ea_srt[(size_t)(qb+e)*2 + 1];
                        float hs = odd ? bf_hi(hr[e]) : bf_lo(hr[e]);
                        float v = fmaxf(hs + edot(A, B, ewr, ebr), 0.f) + 1e-7f;
                        float p = __expf(v - 16.f);    // constant shift, exact in ratio
                        sw += p; swm += p * v;
                    }
                }
            }
            float agg = (sw > 0.f) ? (swm / sw) : 0.f;
            outv[j] = agg + hself;
        }

        // batched MLP: 4 nodes, readlane broadcasts (no LDS-pipe shfl)
        float acc1[4], acc2[4];
        #pragma unroll
        for (int j = 0; j < 4; j++){ acc1[j] = b1a; acc2[j] = b1b; }
        #pragma unroll
        for (int k = 0; k < 64; k++){
            u32 wp = w1p[k*64 + lane];
            float wl = bf_lo(wp), wh = bf_hi(wp);
            #pragma unroll
            for (int j = 0; j < 4; j++){
                float ok = bcastf(outv[j], k);
                acc1[j] = fmaf(ok, wl, acc1[j]);
                acc2[j] = fmaf(ok, wh, acc2[j]);
            }
        }
        float hh1[4], hh2[4], acc[4];
        #pragma unroll
        for (int j = 0; j < 4; j++){
            hh1[j] = fmaxf(fmaf(acc1[j], ga, bba), 0.f);
            hh2[j] = fmaxf(fmaf(acc2[j], gb, bbb), 0.f);
            acc[j] = b2r;
        }
        #pragma unroll
        for (int k = 0; k < 64; k++){
            u32 wp = w2p[k*64 + lane];
            float wl = bf_lo(wp), wh = bf_hi(wp);
            #pragma unroll
            for (int j = 0; j < 4; j++){
                float a1 = bcastf(hh1[j], k);
                float a2 = bcastf(hh2[j], k);
                acc[j] = fmaf(a1, wl, acc[j]);
                acc[j] = fmaf(a2, wh, acc[j]);
            }
        }

        if (cntn == 4){
            // dense full-wave store: LDS transpose 4x[64]u16 -> uint2/lane (512B)
            #pragma unroll
            for (int j = 0; j < 4; j++)
                sb[j*64 + lane] = f2bf(fmaxf(acc[j], 0.f));
            uint2 ov = ((const uint2*)sb)[lane];   // wave-private; lgkmcnt auto
            ((uint2*)(h_out + (size_t)nb*64))[lane] = ov;
        } else {
            for (int j = 0; j < cntn; j++){
                float vfin = fmaxf(acc[j], 0.f);
                float vnext = __shfl_xor(vfin, 1, 64);
                if (!(lane & 1))
                    ((u32*)h_out)[(size_t)(nb+j)*32 + (lane >> 1)] = pack2(vfin, vnext);
            }
        }
    }
}

// ---------------- head: out = concat(h, gf) @ head_w + head_b  (FP32 OUT) ----------------
template<int IS32>
__global__ __launch_bounds__(256) void k_head(const u16* __restrict__ h,
                                              const void* __restrict__ gf,
                                              const int* __restrict__ ngp,
                                              const void* __restrict__ hw,
                                              const void* __restrict__ hb,
                                              const int* __restrict__ flg,
                                              float* __restrict__ out){
    if (flg[0] != IS32) return;
    int lane = threadIdx.x & 63;
    int wid  = (blockIdx.x*256 + threadIdx.x) >> 6;
    int nw   = (gridDim.x*256) >> 6;
    int dw = lane & 31;
    bool active = lane < 32;
    float wc0 = active ? ldx<IS32>(hw, 2*dw)     : 0.f;
    float wc1 = active ? ldx<IS32>(hw, 2*dw + 1) : 0.f;
    float w64 = ldx<IS32>(hw, 64), w65 = ldx<IS32>(hw, 65);
    float bias = ldx<IS32>(hb, 0);
    int ng  = ngp[0];
    if (ng <= 0) ng = 1;
    int npg = NN / ng;
    if (npg <= 0) npg = 1;
    for (int node = wid; node < NN; node += nw){
        float v = 0.f;
        if (active){
            u32 w = ((const u32*)h)[(size_t)node*32 + dw];
            v = bf_lo(w)*wc0 + bf_hi(w)*wc1;
        }
        #pragma unroll
        for (int off = 32; off > 0; off >>= 1) v += __shfl_xor(v, off, 64);
        if (lane == 0){
            int gidx = node / npg, r = node - gidx*npg;
            float g0 = ldx<IS32>(gf, (gidx*2 + 0)*npg + r);
            float g1 = ldx<IS32>(gf, (gidx*2 + 1)*npg + r);
            out[node] = v + g0*w64 + g1*w65 + bias;
        }
    }
}

// ---------------- launch ----------------
extern "C" void kernel_launch(void* const* d_in, const int* in_sizes, int n_in,
                              void* d_out, int out_size, void* d_ws, size_t ws_size,
                              hipStream_t stream){
    const void* x    = d_in[0];
    const int*  ei   = (const int*)d_in[1];          // [2, NE]: row0=src, row1=dst
    const void* ea   = d_in[2];
    const int*  ngp  = (const int*)d_in[3];
    const void* gf   = d_in[4];
    const void* srcw = d_in[5];
    const void* srcb = d_in[6];
    const void* L[16];
    for (int i = 0; i < 16; i++) L[i] = d_in[7 + i];
    const void* headw = d_in[23];
    const void* headb = d_in[24];

    char* ws = (char*)d_ws;
    size_t off = 0;
    auto alloc = [&](size_t bytes) -> void* {
        void* p = ws + off;
        off += (bytes + 255) & ~size_t(255);
        return p;
    };
    u16* hA          = (u16*)  alloc((size_t)NN*64*2);    // 12.8 MB
    u16* hB          = (u16*)  alloc((size_t)NN*64*2);    // 12.8 MB
    int* row_ptr     = (int*)  alloc((size_t)(NN+1)*4);
    int* cnt         = (int*)  alloc((size_t)2*NN*4);     // deg | fill
    int* deg  = cnt;
    int* fill = cnt + NN;
    int* csum        = (int*)  alloc((size_t)NCHUNK*4);
    int* coff        = (int*)  alloc((size_t)NCHUNK*4);
    int* flg         = (int*)  alloc(256);
    int2* pair_sorted= (int2*) alloc((size_t)NE*8);       // 12.8 MB
    uint4* ea_srt    = (uint4*)alloc((size_t)NE*32);      // 51.2 MB
    // total ~= 91 MB — no msg buffer needed

    hipMemsetAsync(cnt, 0, (size_t)2*NN*4, stream);

    const int* e_src = ei;
    const int* e_dst = ei + NE;

    k_sniff      <<<1, 256, 0, stream>>>((const u32*)x, flg);
    k_deg        <<<1024, 256, 0, stream>>>(e_dst, deg);
    k_csum       <<<NCHUNK, 256, 0, stream>>>(deg, csum);
    k_scan_chunks<<<1, 512, 0, stream>>>(csum, coff);
    k_rowptr     <<<NCHUNK, 256, 0, stream>>>(deg, coff, row_ptr);
    k_scatter    <<<1024, 256, 0, stream>>>(e_src, e_dst, row_ptr, fill, pair_sorted);

    k_reorder<1> <<<2048, 256, 0, stream>>>(pair_sorted, ea, flg, ea_srt);
    k_reorder<0> <<<2048, 256, 0, stream>>>(pair_sorted, ea, flg, ea_srt);

    k_proj<1>    <<<512, 256, 0, stream>>>(x, srcw, srcb, flg, hA);
    k_proj<0>    <<<512, 256, 0, stream>>>(x, srcw, srcb, flg, hA);

    // layer 0: hA -> hB
    k_fused<1>   <<<1024, 256, 0, stream>>>(hA, row_ptr, pair_sorted, ea_srt,
                    L[0], L[1], L[2], L[3], L[4], L[5], L[6], L[7], flg, hB);
    k_fused<0>   <<<1024, 256, 0, stream>>>(hA, row_ptr, pair_sorted, ea_srt,
                    L[0], L[1], L[2], L[3], L[4], L[5], L[6], L[7], flg, hB);
    // layer 1: hB -> hA
    k_fused<1>   <<<1024, 256, 0, stream>>>(hB, row_ptr, pair_sorted, ea_srt,
                    L[8], L[9], L[10], L[11], L[12], L[13], L[14], L[15], flg, hA);
    k_fused<0>   <<<1024, 256, 0, stream>>>(hB, row_ptr, pair_sorted, ea_srt,
                    L[8], L[9], L[10], L[11], L[12], L[13], L[14], L[15], flg, hA);

    k_head<1>    <<<512, 256, 0, stream>>>(hA, gf, ngp, headw, headb, flg, (float*)d_out);
    k_head<0>    <<<512, 256, 0, stream>>>(hA, gf, ngp, headw, headb, flg, (float*)d_out);
}